// Round 12
// baseline (453.228 us; speedup 1.0000x reference)
//
#include <hip/hip_runtime.h>
#include <hip/hip_bf16.h>

#define NN 8192
#define KDIM 256
#define DDIM 128

typedef __attribute__((ext_vector_type(8))) short short8;
typedef __attribute__((ext_vector_type(4))) float floatx4;
typedef __attribute__((ext_vector_type(16))) float floatx16;
typedef __attribute__((ext_vector_type(4))) int intx4;

__device__ __forceinline__ unsigned short f2bf(float x) {
    unsigned int u = __float_as_uint(x);
    return (unsigned short)((u + 0x8000u) >> 16);
}

__global__ void k_trip(float* out, float v) {
    if (threadIdx.x == 0 && blockIdx.x == 0) out[0] = v;
}

// ---------------- kA: swizzle W (256x128 fp32 row-major) into bf16 B-fragment layout
// (16x16x32 layout, used by kB's X@W matmul only)
__global__ void kA_swizzleW(const float* __restrict__ W, unsigned short* __restrict__ WB) {
    int gid = blockIdx.x * blockDim.x + threadIdx.x;   // 0..4095
    int kt = gid >> 9, nt = (gid >> 6) & 7, lane = gid & 63;
    int quad = lane >> 4, c = lane & 15;
    short8 pack;
#pragma unroll
    for (int t = 0; t < 8; ++t)
        pack[t] = (short)f2bf(W[(kt * 32 + quad * 8 + t) * DDIM + nt * 16 + c]);
    *(short8*)(WB + ((size_t)(kt * 8 + nt) * 64 + lane) * 8) = pack;
}

// ---------------- kB: Wh = X @ W (bf16 MFMA); emit f, g, and WhB in the
// 32x32x16 B-fragment layout for kC: fragment (jt, dt) = 64 lanes x 8 bf16,
// elem t = Wh[jt*16 + (lane>>5)*8 + t][dt*32 + (lane&31)].
__global__ __launch_bounds__(256) void kB_wh(
        const float* __restrict__ X,
        const unsigned short* __restrict__ WB,
        const float* __restrict__ a,
        unsigned short* __restrict__ WhB,
        float* __restrict__ f, float* __restrict__ g) {
    __shared__ unsigned short tile[64 * 128];
    int tid = threadIdx.x;
    int wave = tid >> 6, lane = tid & 63;
    int quad = lane >> 4, c = lane & 15;
    int rowbase = blockIdx.x * 64 + wave * 16;

    floatx4 acc[8];
#pragma unroll
    for (int nt = 0; nt < 8; ++nt) acc[nt] = (floatx4)(0.0f);

    const short8* WB8 = (const short8*)WB;
#pragma unroll
    for (int ks = 0; ks < 8; ++ks) {
        const float* xp = X + (size_t)(rowbase + c) * KDIM + ks * 32 + quad * 8;
        floatx4 x0 = *(const floatx4*)xp;
        floatx4 x1 = *(const floatx4*)(xp + 4);
        short8 afrag;
#pragma unroll
        for (int t = 0; t < 4; ++t) { afrag[t] = (short)f2bf(x0[t]); afrag[4 + t] = (short)f2bf(x1[t]); }
#pragma unroll
        for (int nt = 0; nt < 8; ++nt) {
            short8 b = WB8[(ks * 8 + nt) * 64 + lane];
            acc[nt] = __builtin_amdgcn_mfma_f32_16x16x32_bf16(afrag, b, acc[nt], 0, 0, 0);
        }
    }

    float fp[4] = {0.f, 0.f, 0.f, 0.f}, gp[4] = {0.f, 0.f, 0.f, 0.f};
#pragma unroll
    for (int nt = 0; nt < 8; ++nt) {
        float a1 = a[nt * 16 + c];
        float a2 = a[DDIM + nt * 16 + c];
#pragma unroll
        for (int r = 0; r < 4; ++r) {
            fp[r] += acc[nt][r] * a1;
            gp[r] += acc[nt][r] * a2;
        }
    }
#pragma unroll
    for (int m = 1; m < 16; m <<= 1) {
#pragma unroll
        for (int r = 0; r < 4; ++r) {
            fp[r] += __shfl_xor(fp[r], m);
            gp[r] += __shfl_xor(gp[r], m);
        }
    }
    if (c == 0) {
#pragma unroll
        for (int r = 0; r < 4; ++r) {
            f[rowbase + quad * 4 + r] = fp[r];
            g[rowbase + quad * 4 + r] = gp[r];
        }
    }

#pragma unroll
    for (int nt = 0; nt < 8; ++nt)
#pragma unroll
        for (int r = 0; r < 4; ++r)
            tile[(wave * 16 + quad * 4 + r) * 128 + nt * 16 + c] = f2bf(acc[nt][r]);
    __syncthreads();

    // swizzle into 32x32x16 B-fragment layout: jt = blockIdx.x*4 + wave
    int half = lane >> 5, c32 = lane & 31;
#pragma unroll
    for (int dt = 0; dt < 4; ++dt) {
        short8 pack;
#pragma unroll
        for (int t = 0; t < 8; ++t)
            pack[t] = (short)tile[(wave * 16 + half * 8 + t) * 128 + dt * 32 + c32];
        *(short8*)(WhB + ((size_t)((blockIdx.x * 4 + wave) * 4 + dt) * 64 + lane) * 8) = pack;
    }
}

// ---------------- kC32: masked-softmax attention, 32 ROWS/BLOCK via 32x32x16 MFMA.
// HISTORY: R6 16-row/2-way = ~118us; R9 occupancy-up = neutral; R10 load-order =
// neutral; R11 NT = neutral. Little's-law readout: WhB re-reads = 1.07 GB in
// ~110us ~= 9.7 TB/s from L2/L3 — kC is MEMORY-SUPPLY-bound on WhB bytes, and
// WhB traffic scales as 1/(rows per block). This kernel: 32 rows/block (halves
// WhB traffic). 4 waves share each 8KB WhB j-tile; wave w owns d-slice
// [w*32,w*32+32) -> acc is ONE f32x16 (16 AGPR), bfr dbuf 16 VGPR, ~110 total ->
// still 4 blocks/CU. All waves compute P redundantly (VALU at 12% = free);
// adjacency dup-loads served by L1. Cross-wave acc-merge DELETED (waves own
// disjoint output columns); l-sum via one shfl_xor. LDS = 8.2 KB.
__global__ __launch_bounds__(256, 4) void kC_attn32(
        const int* __restrict__ adj,
        const unsigned short* __restrict__ WhB,
        const float* __restrict__ f, const float* __restrict__ g,
        float* __restrict__ pacc, float* __restrict__ pl) {
    __shared__ float smem[2048];         // 8 KB: this quarter's g-slice
    int tid = threadIdx.x;
    int wave = tid >> 6, lane = tid & 63;
    int half = lane >> 5, r32 = lane & 31;
    int bq   = blockIdx.x >> 8;          // column quarter 0..3
    int brow = blockIdx.x & 255;         // 32-row group
    int rowbase = brow * 32;

    {
        const floatx4* g4 = (const floatx4*)g;
        for (int i = tid; i < 512; i += 256)
            ((floatx4*)smem)[i] = g4[bq * 512 + i];
    }
    __syncthreads();

    float f0 = f[rowbase + r32];

    floatx16 acc = (floatx16)(0.0f);
    float l0 = 0.0f;

    const intx4* arow = (const intx4*)(adj + (size_t)(rowbase + r32) * NN);
    const short8* WhB8 = (const short8*)WhB;
    int jb = bq * 64;                    // J32 range [jb, jb+64)

    // adjacency prefetch 2-deep (4 intx4/step: kt0 cols half*8..+7, kt1 +16)
    intx4 A00, A01, A02, A03, A10, A11, A12, A13;
    {
        int i0 = (jb + 0) * 8 + half * 2;
        A00 = arow[i0]; A01 = arow[i0 + 1]; A02 = arow[i0 + 4]; A03 = arow[i0 + 5];
        int i1 = (jb + 1) * 8 + half * 2;
        A10 = arow[i1]; A11 = arow[i1 + 1]; A12 = arow[i1 + 4]; A13 = arow[i1 + 5];
    }

    // WhB fragment prefetch for it=0 (2 kt fragments, own dt = wave)
    short8 bfrA0, bfrA1, bfrB0, bfrB1;
    bfrA0 = WhB8[((size_t)((jb + 0) * 2 + 0) * 4 + wave) * 64 + lane];
    bfrA1 = WhB8[((size_t)((jb + 0) * 2 + 1) * 4 + wave) * 64 + lane];

#define KC_STEP(ITC, BC0, BC1, BN0, BN1) do {                                   \
        int J32n_ = jb + (((ITC) + 1) & 63);                                    \
        BN0 = WhB8[((size_t)(J32n_ * 2 + 0) * 4 + wave) * 64 + lane];           \
        BN1 = WhB8[((size_t)(J32n_ * 2 + 1) * 4 + wave) * 64 + lane];           \
        int ja_ = (jb + (((ITC) + 2) & 63)) * 8 + half * 2;                     \
        intx4 L0_ = arow[ja_],     L1_ = arow[ja_ + 1];                         \
        intx4 L2_ = arow[ja_ + 4], L3_ = arow[ja_ + 5];                         \
        int gb_ = (ITC) * 32 + half * 8;                                        \
        floatx4 g0_ = *(const floatx4*)&smem[gb_];                              \
        floatx4 g1_ = *(const floatx4*)&smem[gb_ + 4];                          \
        floatx4 g2_ = *(const floatx4*)&smem[gb_ + 16];                         \
        floatx4 g3_ = *(const floatx4*)&smem[gb_ + 20];                         \
        short8 af0_, af1_;                                                      \
        _Pragma("unroll")                                                       \
        for (int u = 0; u < 4; ++u) {                                           \
            float x_, E_;                                                       \
            x_ = f0 + g0_[u]; x_ = fmaxf(x_, 0.2f * x_);                        \
            E_ = (A00[u] > 0) ? __expf(x_) : 0.0f; l0 += E_;                    \
            af0_[u] = (short)f2bf(E_);                                          \
            x_ = f0 + g1_[u]; x_ = fmaxf(x_, 0.2f * x_);                        \
            E_ = (A01[u] > 0) ? __expf(x_) : 0.0f; l0 += E_;                    \
            af0_[4 + u] = (short)f2bf(E_);                                      \
            x_ = f0 + g2_[u]; x_ = fmaxf(x_, 0.2f * x_);                        \
            E_ = (A02[u] > 0) ? __expf(x_) : 0.0f; l0 += E_;                    \
            af1_[u] = (short)f2bf(E_);                                          \
            x_ = f0 + g3_[u]; x_ = fmaxf(x_, 0.2f * x_);                        \
            E_ = (A03[u] > 0) ? __expf(x_) : 0.0f; l0 += E_;                    \
            af1_[4 + u] = (short)f2bf(E_);                                      \
        }                                                                       \
        acc = __builtin_amdgcn_mfma_f32_32x32x16_bf16(af0_, BC0, acc, 0, 0, 0); \
        acc = __builtin_amdgcn_mfma_f32_32x32x16_bf16(af1_, BC1, acc, 0, 0, 0); \
        A00 = A10; A01 = A11; A02 = A12; A03 = A13;                             \
        A10 = L0_; A11 = L1_; A12 = L2_; A13 = L3_;                             \
    } while (0)

    for (int it = 0; it < 64; it += 2) {
        KC_STEP(it, bfrA0, bfrA1, bfrB0, bfrB1);
        KC_STEP(it + 1, bfrB0, bfrB1, bfrA0, bfrA1);
    }
#undef KC_STEP

    // ---- l partial: lanes l and l+32 hold the two j-half sums of row (l&31).
    // All 4 waves computed identical P; wave 0 writes.
    float lsum = l0 + __shfl_xor(l0, 32);
    if (wave == 0 && lane < 32)
        pl[bq * NN + rowbase + lane] = lsum;

    // ---- write partial acc: wave w owns d-cols [w*32, w*32+32), no merge.
    // D layout (m74/m101): col = lane&31, row = (reg&3) + 8*(reg>>2) + 4*(lane>>5)
    float* pb = pacc + (size_t)bq * NN * DDIM;
#pragma unroll
    for (int reg = 0; reg < 16; ++reg) {
        int irow = (reg & 3) + 8 * (reg >> 2) + 4 * half;
        pb[(size_t)(rowbase + irow) * DDIM + wave * 32 + r32] = acc[reg];
    }
}

// ---------------- kD4: merge 4 column-quarter partials, normalize, ELU, store.
__global__ __launch_bounds__(256) void kD_merge4(
        const float* __restrict__ pacc, const float* __restrict__ pl,
        float* __restrict__ out) {
    int i = blockIdx.x * 256 + threadIdx.x;          // floatx4 index, 262144 total
    const int Q = NN * DDIM / 4;
    const floatx4* p4 = (const floatx4*)pacc;
    floatx4 a0 = p4[i], a1 = p4[i + Q], a2 = p4[i + 2 * Q], a3 = p4[i + 3 * Q];
    int row = i >> 5;                                // 32 floatx4 per row
    float s = pl[row] + pl[NN + row] + pl[2 * NN + row] + pl[3 * NN + row];
    float inv = (s > 0.0f) ? 1.0f / s : 0.0f;
    floatx4 h;
#pragma unroll
    for (int r = 0; r < 4; ++r) {
        float v = (a0[r] + a1[r] + a2[r] + a3[r]) * inv;
        h[r] = (v > 0.0f) ? v : expm1f(v);
    }
    ((floatx4*)out)[i] = h;
}

extern "C" void kernel_launch(void* const* d_in, const int* in_sizes, int n_in,
                              void* d_out, int out_size, void* d_ws, size_t ws_size,
                              hipStream_t stream) {
    float* out = (float*)d_out;

    const void *p_adj = nullptr, *p_X = nullptr, *p_W = nullptr, *p_a = nullptr;
    for (int i = 0; i < n_in; ++i) {
        switch (in_sizes[i]) {
            case NN * NN:     p_adj = d_in[i]; break;
            case NN * KDIM:   p_X   = d_in[i]; break;
            case KDIM * DDIM: p_W   = d_in[i]; break;
            case 2 * DDIM:    p_a   = d_in[i]; break;
            default: break;
        }
    }
    if (!p_adj || !p_X || !p_W || !p_a) {
        k_trip<<<dim3(1), dim3(64), 0, stream>>>(out, 99999.0f);
        return;
    }

    size_t off_WB   = 0;                                   // 64 KB
    size_t off_WhB  = off_WB + 65536;                      // 2 MB
    size_t off_f    = off_WhB + (size_t)NN * DDIM * 2;     // 32 KB
    size_t off_g    = off_f + NN * 4;                      // 32 KB
    size_t off_pacc = off_g + NN * 4;                      // 4 x 4 MB partial acc
    size_t off_pl   = off_pacc + (size_t)4 * NN * DDIM * 4;// 4 x 32 KB partial l
    size_t needed   = off_pl + (size_t)4 * NN * 4;         // ~18.6 MB (fits: R8/R9 ran 4-way)
    if (ws_size < needed) {
        k_trip<<<dim3(1), dim3(64), 0, stream>>>(out, 12345.0f);
        return;
    }
    char* ws = (char*)d_ws;
    unsigned short* WB   = (unsigned short*)(ws + off_WB);
    unsigned short* WhB  = (unsigned short*)(ws + off_WhB);
    float*          f    = (float*)(ws + off_f);
    float*          g    = (float*)(ws + off_g);
    float*          pacc = (float*)(ws + off_pacc);
    float*          pl   = (float*)(ws + off_pl);

    const int*   adj = (const int*)p_adj;
    const float* X   = (const float*)p_X;
    const float* W   = (const float*)p_W;
    const float* a   = (const float*)p_a;

    kA_swizzleW<<<dim3(16), dim3(256), 0, stream>>>(W, WB);
    kB_wh<<<dim3(128), dim3(256), 0, stream>>>(X, WB, a, WhB, f, g);
    kC_attn32<<<dim3(1024), dim3(256), 0, stream>>>(adj, WhB, f, g, pacc, pl);
    kD_merge4<<<dim3(NN * DDIM / 4 / 256), dim3(256), 0, stream>>>(pacc, pl, out);
}

// Round 13
// 420.234 us; speedup vs baseline: 1.0785x; 1.0785x over previous
//
#include <hip/hip_runtime.h>
#include <hip/hip_bf16.h>

#define NN 8192
#define KDIM 256
#define DDIM 128

typedef __attribute__((ext_vector_type(8))) short short8;
typedef __attribute__((ext_vector_type(4))) float floatx4;
typedef __attribute__((ext_vector_type(4))) int intx4;

__device__ __forceinline__ unsigned short f2bf(float x) {
    unsigned int u = __float_as_uint(x);
    return (unsigned short)((u + 0x8000u) >> 16);
}

__global__ void k_trip(float* out, float v) {
    if (threadIdx.x == 0 && blockIdx.x == 0) out[0] = v;
}

// ---------------- kP: bitpack adjacency 268 MB int32 -> 8 MB bits.
// adjb[row*256 + j32] bit b = (adj[row][j32*32+b] > 0). One thread per uint;
// reads 8 intx4 (stream, every line consumed), writes coalesced.
__global__ __launch_bounds__(256) void kP_bitpack(const int* __restrict__ adj,
                                                  unsigned int* __restrict__ adjb) {
    int gid = blockIdx.x * 256 + threadIdx.x;       // 0..2097151
    int row = gid >> 8, j32 = gid & 255;
    const intx4* p = (const intx4*)(adj + (size_t)row * NN + j32 * 32);
    unsigned int bits = 0;
#pragma unroll
    for (int r = 0; r < 8; ++r) {
        intx4 v = p[r];
#pragma unroll
        for (int e = 0; e < 4; ++e)
            if (v[e] > 0) bits |= (1u << (r * 4 + e));
    }
    adjb[gid] = bits;
}

// ---------------- kA: swizzle W into bf16 16x16x32 B-fragment layout
__global__ void kA_swizzleW(const float* __restrict__ W, unsigned short* __restrict__ WB) {
    int gid = blockIdx.x * blockDim.x + threadIdx.x;   // 0..4095
    int kt = gid >> 9, nt = (gid >> 6) & 7, lane = gid & 63;
    int quad = lane >> 4, c = lane & 15;
    short8 pack;
#pragma unroll
    for (int t = 0; t < 8; ++t)
        pack[t] = (short)f2bf(W[(kt * 32 + quad * 8 + t) * DDIM + nt * 16 + c]);
    *(short8*)(WB + ((size_t)(kt * 8 + nt) * 64 + lane) * 8) = pack;
}

// ---------------- kB: Wh = X @ W; emit f, g, and WhB fragments (16x16x32 layout,
// fragment (J32, nt) — the R6-verified layout).
__global__ __launch_bounds__(256) void kB_wh(
        const float* __restrict__ X,
        const unsigned short* __restrict__ WB,
        const float* __restrict__ a,
        unsigned short* __restrict__ WhB,
        float* __restrict__ f, float* __restrict__ g) {
    __shared__ unsigned short tile[64 * 128];
    int tid = threadIdx.x;
    int wave = tid >> 6, lane = tid & 63;
    int quad = lane >> 4, c = lane & 15;
    int rowbase = blockIdx.x * 64 + wave * 16;

    floatx4 acc[8];
#pragma unroll
    for (int nt = 0; nt < 8; ++nt) acc[nt] = (floatx4)(0.0f);

    const short8* WB8 = (const short8*)WB;
#pragma unroll
    for (int ks = 0; ks < 8; ++ks) {
        const float* xp = X + (size_t)(rowbase + c) * KDIM + ks * 32 + quad * 8;
        floatx4 x0 = *(const floatx4*)xp;
        floatx4 x1 = *(const floatx4*)(xp + 4);
        short8 afrag;
#pragma unroll
        for (int t = 0; t < 4; ++t) { afrag[t] = (short)f2bf(x0[t]); afrag[4 + t] = (short)f2bf(x1[t]); }
#pragma unroll
        for (int nt = 0; nt < 8; ++nt) {
            short8 b = WB8[(ks * 8 + nt) * 64 + lane];
            acc[nt] = __builtin_amdgcn_mfma_f32_16x16x32_bf16(afrag, b, acc[nt], 0, 0, 0);
        }
    }

    float fp[4] = {0.f, 0.f, 0.f, 0.f}, gp[4] = {0.f, 0.f, 0.f, 0.f};
#pragma unroll
    for (int nt = 0; nt < 8; ++nt) {
        float a1 = a[nt * 16 + c];
        float a2 = a[DDIM + nt * 16 + c];
#pragma unroll
        for (int r = 0; r < 4; ++r) {
            fp[r] += acc[nt][r] * a1;
            gp[r] += acc[nt][r] * a2;
        }
    }
#pragma unroll
    for (int m = 1; m < 16; m <<= 1) {
#pragma unroll
        for (int r = 0; r < 4; ++r) {
            fp[r] += __shfl_xor(fp[r], m);
            gp[r] += __shfl_xor(gp[r], m);
        }
    }
    if (c == 0) {
#pragma unroll
        for (int r = 0; r < 4; ++r) {
            f[rowbase + quad * 4 + r] = fp[r];
            g[rowbase + quad * 4 + r] = gp[r];
        }
    }

#pragma unroll
    for (int nt = 0; nt < 8; ++nt)
#pragma unroll
        for (int r = 0; r < 4; ++r)
            tile[(wave * 16 + quad * 4 + r) * 128 + nt * 16 + c] = f2bf(acc[nt][r]);
    __syncthreads();

    int kt2 = wave >> 1;
#pragma unroll
    for (int ntj = 0; ntj < 4; ++ntj) {
        int nt = (wave & 1) * 4 + ntj;
        short8 pack;
#pragma unroll
        for (int t = 0; t < 8; ++t)
            pack[t] = (short)tile[(kt2 * 32 + quad * 8 + t) * 128 + nt * 16 + c];
        *(short8*)(WhB + ((size_t)((blockIdx.x * 2 + kt2) * 8 + nt) * 64 + lane) * 8) = pack;
    }
}

// ---------------- kC32q: 32 rows/block, 4-way column split, bitpacked adjacency.
// MATRIX: R6 16-row = 118us (best); R9/R10/R11 occupancy/order/NT = neutral;
// R12 32-row-redundant = 180us (VALU 41% — waves duplicated P; wrong partition).
// MODEL: WhB re-reads (1.07 GB @ ~9.7 TB/s) are served by L3 because the 268-MB
// adjacency stream evicts WhB from per-XCD L2; L3 supply is the binder.
// THIS KERNEL: waves still split j (NO redundancy); each wave computes TWO
// 16-row A-frags (acc0/acc1) against the SAME WhB tile -> WhB bytes HALVED.
// Adjacency comes from kP's 8-MB bitpack -> no L2-evicting stream, 4 regs not 32
// (the enabler for acc0+acc1+dbuf to fit ~160 VGPR at (256,3)).
__global__ __launch_bounds__(256, 3) void kC_attn32q(
        const unsigned int* __restrict__ adjb,
        const unsigned short* __restrict__ WhB,
        const float* __restrict__ f, const float* __restrict__ g,
        float* __restrict__ pacc, float* __restrict__ pl) {
    __shared__ float smem[5120];   // 20.5 KB: [0,2048) g-slice; merge overlay after
    int tid = threadIdx.x;
    int wave = tid >> 6, lane = tid & 63;
    int quad = lane >> 4, c = lane & 15;
    int bq   = blockIdx.x >> 8;          // column quarter 0..3
    int brow = blockIdx.x & 255;         // 32-row group
    int rowbase = brow * 32;

    {
        const floatx4* g4 = (const floatx4*)g;
        for (int i = tid; i < 512; i += 256)
            ((floatx4*)smem)[i] = g4[bq * 512 + i];
    }
    __syncthreads();

    float f0 = f[rowbase + c];
    float f1 = f[rowbase + 16 + c];

    floatx4 acc0[8], acc1[8];
#pragma unroll
    for (int nt = 0; nt < 8; ++nt) { acc0[nt] = (floatx4)(0.0f); acc1[nt] = (floatx4)(0.0f); }
    float l0 = 0.0f, l1 = 0.0f;

    const unsigned int* ab0 = adjb + (size_t)(rowbase + c) * 256;
    const unsigned int* ab1 = adjb + (size_t)(rowbase + 16 + c) * 256;
    const short8* WhB8 = (const short8*)WhB;
    int jbase = bq * 64;                 // J32 range [jbase, jbase+64)

    // prefetch bits + WhB tile for it=0
    unsigned int cb0 = ab0[jbase + wave];
    unsigned int cb1 = ab1[jbase + wave];
    short8 bfrA[8], bfrB[8];
#pragma unroll
    for (int nt = 0; nt < 8; ++nt)
        bfrA[nt] = WhB8[((size_t)(jbase + wave) * 8 + nt) * 64 + lane];

#define KC_STEP(ITC, BCUR, BNEXT) do {                                          \
        int J32n_ = jbase + (((ITC) + 1) & 15) * 4 + wave;                      \
        _Pragma("unroll")                                                       \
        for (int nt = 0; nt < 8; ++nt)                                          \
            BNEXT[nt] = WhB8[((size_t)J32n_ * 8 + nt) * 64 + lane];             \
        unsigned int nb0_ = ab0[J32n_], nb1_ = ab1[J32n_];                      \
        int gb_ = (((ITC) * 4 + wave)) * 32 + quad * 8;                         \
        floatx4 g0_ = *(const floatx4*)&smem[gb_];                              \
        floatx4 g1_ = *(const floatx4*)&smem[gb_ + 4];                          \
        unsigned int b0_ = cb0 >> (quad * 8);                                   \
        unsigned int b1_ = cb1 >> (quad * 8);                                   \
        short8 afr_;                                                            \
        _Pragma("unroll")                                                       \
        for (int u = 0; u < 4; ++u) {                                           \
            float x_, E_;                                                       \
            x_ = f0 + g0_[u]; x_ = fmaxf(x_, 0.2f * x_);                        \
            E_ = ((b0_ >> u) & 1u) ? __expf(x_) : 0.0f; l0 += E_;               \
            afr_[u] = (short)f2bf(E_);                                          \
            x_ = f0 + g1_[u]; x_ = fmaxf(x_, 0.2f * x_);                        \
            E_ = ((b0_ >> (4 + u)) & 1u) ? __expf(x_) : 0.0f; l0 += E_;         \
            afr_[4 + u] = (short)f2bf(E_);                                      \
        }                                                                       \
        _Pragma("unroll")                                                       \
        for (int nt = 0; nt < 8; ++nt)                                          \
            acc0[nt] = __builtin_amdgcn_mfma_f32_16x16x32_bf16(afr_, BCUR[nt],  \
                                                               acc0[nt], 0, 0, 0);\
        _Pragma("unroll")                                                       \
        for (int u = 0; u < 4; ++u) {                                           \
            float x_, E_;                                                       \
            x_ = f1 + g0_[u]; x_ = fmaxf(x_, 0.2f * x_);                        \
            E_ = ((b1_ >> u) & 1u) ? __expf(x_) : 0.0f; l1 += E_;               \
            afr_[u] = (short)f2bf(E_);                                          \
            x_ = f1 + g1_[u]; x_ = fmaxf(x_, 0.2f * x_);                        \
            E_ = ((b1_ >> (4 + u)) & 1u) ? __expf(x_) : 0.0f; l1 += E_;         \
            afr_[4 + u] = (short)f2bf(E_);                                      \
        }                                                                       \
        _Pragma("unroll")                                                       \
        for (int nt = 0; nt < 8; ++nt)                                          \
            acc1[nt] = __builtin_amdgcn_mfma_f32_16x16x32_bf16(afr_, BCUR[nt],  \
                                                               acc1[nt], 0, 0, 0);\
        cb0 = nb0_; cb1 = nb1_;                                                 \
    } while (0)

    for (int it = 0; it < 16; it += 2) {
        KC_STEP(it, bfrA, bfrB);
        KC_STEP(it + 1, bfrB, bfrA);
    }
#undef KC_STEP

    // ---- l partials (rows 0-15 at [4608,4864), rows 16-31 at [4864,5120)) ----
    __syncthreads();                      // g region dead; smem reusable
    smem[4608 + wave * 64 + lane] = l0;
    smem[4864 + wave * 64 + lane] = l1;
    __syncthreads();
    if (tid < 32) {
        int rg = tid >> 4, t = tid & 15;
        float s = 0.0f;
#pragma unroll
        for (int w = 0; w < 4; ++w)
#pragma unroll
            for (int q = 0; q < 4; ++q)
                s += smem[4608 + rg * 256 + w * 64 + q * 16 + t];
        pl[bq * NN + rowbase + rg * 16 + t] = s;
    }

    // ---- acc merge across 4 waves, per row-group (stride-36 buffers [0,4608)) --
#define MERGE_RG(ACC, ROWOFF) do {                                              \
        __syncthreads();                                                        \
        if (wave >= 2) {                                                        \
            float* b = &smem[(wave - 2) * 2304 + lane * 36];                    \
            _Pragma("unroll")                                                   \
            for (int nt = 0; nt < 8; ++nt) *(floatx4*)&b[nt * 4] = ACC[nt];     \
        }                                                                       \
        __syncthreads();                                                        \
        if (wave < 2) {                                                         \
            float* b = &smem[wave * 2304 + lane * 36];                          \
            _Pragma("unroll")                                                   \
            for (int nt = 0; nt < 8; ++nt) ACC[nt] += *(const floatx4*)&b[nt * 4];\
        }                                                                       \
        __syncthreads();                                                        \
        if (wave == 1) {                                                        \
            float* b = &smem[lane * 36];                                        \
            _Pragma("unroll")                                                   \
            for (int nt = 0; nt < 8; ++nt) *(floatx4*)&b[nt * 4] = ACC[nt];     \
        }                                                                       \
        __syncthreads();                                                        \
        if (wave == 0) {                                                        \
            float* b = &smem[lane * 36];                                        \
            _Pragma("unroll")                                                   \
            for (int nt = 0; nt < 8; ++nt) ACC[nt] += *(const floatx4*)&b[nt * 4];\
            float* pb = pacc + (size_t)bq * NN * DDIM;                          \
            _Pragma("unroll")                                                   \
            for (int nt = 0; nt < 8; ++nt)                                      \
                _Pragma("unroll")                                               \
                for (int r = 0; r < 4; ++r)                                     \
                    pb[(size_t)(rowbase + (ROWOFF) + quad * 4 + r) * DDIM       \
                       + nt * 16 + c] = ACC[nt][r];                             \
        }                                                                       \
    } while (0)

    MERGE_RG(acc0, 0);
    MERGE_RG(acc1, 16);
#undef MERGE_RG
}

// ---------------- kD4: merge 4 column-quarter partials, normalize, ELU, store.
__global__ __launch_bounds__(256) void kD_merge4(
        const float* __restrict__ pacc, const float* __restrict__ pl,
        float* __restrict__ out) {
    int i = blockIdx.x * 256 + threadIdx.x;          // floatx4 index, 262144 total
    const int Q = NN * DDIM / 4;
    const floatx4* p4 = (const floatx4*)pacc;
    floatx4 a0 = p4[i], a1 = p4[i + Q], a2 = p4[i + 2 * Q], a3 = p4[i + 3 * Q];
    int row = i >> 5;                                // 32 floatx4 per row
    float s = pl[row] + pl[NN + row] + pl[2 * NN + row] + pl[3 * NN + row];
    float inv = (s > 0.0f) ? 1.0f / s : 0.0f;
    floatx4 h;
#pragma unroll
    for (int r = 0; r < 4; ++r) {
        float v = (a0[r] + a1[r] + a2[r] + a3[r]) * inv;
        h[r] = (v > 0.0f) ? v : expm1f(v);
    }
    ((floatx4*)out)[i] = h;
}

// ---------------- Fallback path: the measured-neutral R10 2-way 16-row kernels.
__global__ __launch_bounds__(256, 4) void kC_attn2(
        const int* __restrict__ adj,
        const unsigned short* __restrict__ WhB,
        const float* __restrict__ f, const float* __restrict__ g,
        float* __restrict__ pacc, float* __restrict__ pl) {
    __shared__ float smem[8192];
    int tid = threadIdx.x;
    int wave = tid >> 6, lane = tid & 63;
    int quad = lane >> 4, c = lane & 15;
    int bq   = blockIdx.x >> 9;
    int brow = blockIdx.x & 511;
    int rowbase = brow * 16;

    {
        const floatx4* g4 = (const floatx4*)g;
        for (int i = tid; i < 1024; i += 256)
            ((floatx4*)smem)[i] = g4[bq * 1024 + i];
    }
    __syncthreads();

    float f0 = f[rowbase + c];

    floatx4 acc[8];
#pragma unroll
    for (int nt = 0; nt < 8; ++nt) acc[nt] = (floatx4)(0.0f);
    float l0 = 0.0f;

    const intx4* arow = (const intx4*)(adj + (size_t)(rowbase + c) * NN);
    const short8* WhB8 = (const short8*)WhB;
    int jbase = bq * 128;

    intx4 A0a = arow[(jbase + 0 * 4 + wave) * 8 + quad * 2];
    intx4 A0b = arow[(jbase + 0 * 4 + wave) * 8 + quad * 2 + 1];
    intx4 A1a = arow[(jbase + 1 * 4 + wave) * 8 + quad * 2];
    intx4 A1b = arow[(jbase + 1 * 4 + wave) * 8 + quad * 2 + 1];

    short8 bfrA[8], bfrB[8];
#pragma unroll
    for (int nt = 0; nt < 8; ++nt)
        bfrA[nt] = WhB8[((size_t)(jbase + wave) * 8 + nt) * 64 + lane];

#define KC_STEP(ITC, BCUR, BNEXT) do {                                          \
        int J32n_ = jbase + (((ITC) + 1) & 31) * 4 + wave;                      \
        _Pragma("unroll")                                                       \
        for (int nt = 0; nt < 8; ++nt)                                          \
            BNEXT[nt] = WhB8[((size_t)J32n_ * 8 + nt) * 64 + lane];             \
        int j4n_ = jbase + (((ITC) + 2) & 31) * 4 + wave;                       \
        intx4 A2a_ = arow[j4n_ * 8 + quad * 2];                                 \
        intx4 A2b_ = arow[j4n_ * 8 + quad * 2 + 1];                             \
        int gb_ = ((ITC) * 4 + wave) * 32 + quad * 8;                           \
        floatx4 g0_ = *(const floatx4*)&smem[gb_];                              \
        floatx4 g1_ = *(const floatx4*)&smem[gb_ + 4];                          \
        short8 afr_;                                                            \
        _Pragma("unroll")                                                       \
        for (int u = 0; u < 4; ++u) {                                           \
            float x_, E_;                                                       \
            x_ = f0 + g0_[u]; x_ = fmaxf(x_, 0.2f * x_);                        \
            E_ = (A0a[u] > 0) ? __expf(x_) : 0.0f; l0 += E_;                    \
            afr_[u] = (short)f2bf(E_);                                          \
            x_ = f0 + g1_[u]; x_ = fmaxf(x_, 0.2f * x_);                        \
            E_ = (A0b[u] > 0) ? __expf(x_) : 0.0f; l0 += E_;                    \
            afr_[4 + u] = (short)f2bf(E_);                                      \
        }                                                                       \
        _Pragma("unroll")                                                       \
        for (int nt = 0; nt < 8; ++nt)                                          \
            acc[nt] = __builtin_amdgcn_mfma_f32_16x16x32_bf16(afr_, BCUR[nt],   \
                                                              acc[nt], 0, 0, 0);\
        A0a = A1a; A0b = A1b; A1a = A2a_; A1b = A2b_;                           \
    } while (0)

    for (int it = 0; it < 32; it += 2) {
        KC_STEP(it, bfrA, bfrB);
        KC_STEP(it + 1, bfrB, bfrA);
    }
#undef KC_STEP

    __syncthreads();
    smem[7000 + wave * 64 + lane] = l0;
    __syncthreads();
    if (tid < 16) {
        float s = 0.0f;
#pragma unroll
        for (int w = 0; w < 4; ++w)
#pragma unroll
            for (int q = 0; q < 4; ++q)
                s += smem[7000 + w * 64 + q * 16 + tid];
        pl[bq * NN + rowbase + tid] = s;
    }

    if (wave >= 2) {
        float* b = &smem[(wave - 2) * 2304 + lane * 36];
#pragma unroll
        for (int nt = 0; nt < 8; ++nt) *(floatx4*)&b[nt * 4] = acc[nt];
    }
    __syncthreads();
    if (wave < 2) {
        float* b = &smem[wave * 2304 + lane * 36];
#pragma unroll
        for (int nt = 0; nt < 8; ++nt) acc[nt] += *(const floatx4*)&b[nt * 4];
    }
    __syncthreads();
    if (wave == 1) {
        float* b = &smem[lane * 36];
#pragma unroll
        for (int nt = 0; nt < 8; ++nt) *(floatx4*)&b[nt * 4] = acc[nt];
    }
    __syncthreads();

    if (wave == 0) {
        float* b = &smem[lane * 36];
#pragma unroll
        for (int nt = 0; nt < 8; ++nt) acc[nt] += *(const floatx4*)&b[nt * 4];
        float* pb = pacc + (size_t)bq * NN * DDIM;
#pragma unroll
        for (int nt = 0; nt < 8; ++nt)
#pragma unroll
            for (int r = 0; r < 4; ++r)
                pb[(size_t)(rowbase + quad * 4 + r) * DDIM + nt * 16 + c] = acc[nt][r];
    }
}

__global__ __launch_bounds__(256) void kD_merge2(
        const float* __restrict__ pacc, const float* __restrict__ pl,
        float* __restrict__ out) {
    int i = blockIdx.x * 256 + threadIdx.x;
    const floatx4* p4 = (const floatx4*)pacc;
    floatx4 a = p4[i];
    floatx4 b = p4[i + NN * DDIM / 4];
    int row = i >> 5;
    float s = pl[row] + pl[NN + row];
    float inv = (s > 0.0f) ? 1.0f / s : 0.0f;
    floatx4 h;
#pragma unroll
    for (int r = 0; r < 4; ++r) {
        float v = (a[r] + b[r]) * inv;
        h[r] = (v > 0.0f) ? v : expm1f(v);
    }
    ((floatx4*)out)[i] = h;
}

extern "C" void kernel_launch(void* const* d_in, const int* in_sizes, int n_in,
                              void* d_out, int out_size, void* d_ws, size_t ws_size,
                              hipStream_t stream) {
    float* out = (float*)d_out;

    const void *p_adj = nullptr, *p_X = nullptr, *p_W = nullptr, *p_a = nullptr;
    for (int i = 0; i < n_in; ++i) {
        switch (in_sizes[i]) {
            case NN * NN:     p_adj = d_in[i]; break;
            case NN * KDIM:   p_X   = d_in[i]; break;
            case KDIM * DDIM: p_W   = d_in[i]; break;
            case 2 * DDIM:    p_a   = d_in[i]; break;
            default: break;
        }
    }
    if (!p_adj || !p_X || !p_W || !p_a) {
        k_trip<<<dim3(1), dim3(64), 0, stream>>>(out, 99999.0f);
        return;
    }

    size_t off_WB   = 0;                                    // 64 KB
    size_t off_WhB  = off_WB + 65536;                       // 2 MB
    size_t off_f    = off_WhB + (size_t)NN * DDIM * 2;      // 32 KB
    size_t off_g    = off_f + NN * 4;                       // 32 KB
    size_t off_pacc = off_g + NN * 4;
    size_t needed4  = off_pacc + (size_t)4 * NN * DDIM * 4  // 16 MB pacc
                      + (size_t)4 * NN * 4                  // 128 KB pl
                      + (size_t)NN * 256 * 4;               // 8 MB adjb  => ~26.6 MB
    size_t needed2  = off_pacc + (size_t)2 * NN * DDIM * 4 + (size_t)2 * NN * 4;
    if (ws_size < needed2) {
        k_trip<<<dim3(1), dim3(64), 0, stream>>>(out, 12345.0f);
        return;
    }
    char* ws = (char*)d_ws;
    unsigned short* WB   = (unsigned short*)(ws + off_WB);
    unsigned short* WhB  = (unsigned short*)(ws + off_WhB);
    float*          f    = (float*)(ws + off_f);
    float*          g    = (float*)(ws + off_g);
    float*          pacc = (float*)(ws + off_pacc);

    const int*   adj = (const int*)p_adj;
    const float* X   = (const float*)p_X;
    const float* W   = (const float*)p_W;
    const float* a   = (const float*)p_a;

    if (ws_size >= needed4) {
        float*        pl   = (float*)(ws + off_pacc + (size_t)4 * NN * DDIM * 4);
        unsigned int* adjb = (unsigned int*)(ws + off_pacc + (size_t)4 * NN * DDIM * 4
                                             + (size_t)4 * NN * 4);
        // kP first: its 268-MB stream finishes before kB writes WhB (keeps WhB warm).
        kP_bitpack<<<dim3(NN * 256 / 256), dim3(256), 0, stream>>>(adj, adjb);
        kA_swizzleW<<<dim3(16), dim3(256), 0, stream>>>(W, WB);
        kB_wh<<<dim3(128), dim3(256), 0, stream>>>(X, WB, a, WhB, f, g);
        kC_attn32q<<<dim3(1024), dim3(256), 0, stream>>>(adjb, WhB, f, g, pacc, pl);
        kD_merge4<<<dim3(NN * DDIM / 4 / 256), dim3(256), 0, stream>>>(pacc, pl, out);
    } else {
        float* pl = (float*)(ws + off_pacc + (size_t)2 * NN * DDIM * 4);
        kA_swizzleW<<<dim3(16), dim3(256), 0, stream>>>(W, WB);
        kB_wh<<<dim3(128), dim3(256), 0, stream>>>(X, WB, a, WhB, f, g);
        kC_attn2<<<dim3(1024), dim3(256), 0, stream>>>(adj, WhB, f, g, pacc, pl);
        kD_merge2<<<dim3(NN * DDIM / 4 / 256), dim3(256), 0, stream>>>(pacc, pl, out);
    }
}